// Round 8
// baseline (69.103 us; speedup 1.0000x reference)
//
#include <hip/hip_runtime.h>
#include <hip/hip_cooperative_groups.h>

namespace cg = cooperative_groups;

#define B_ 16
#define N_ 2048
#define ITILE 64                   // rows per block, 2 per thread
#define NBLK (N_ / ITILE)          // 32 blocks per batch
#define NBLOCKS (B_ * NBLK)        // 512 total (2 blocks/CU -> cooperative-safe)

// HW transcendentals: v_exp_f32 (2^x) and v_log_f32 (log2 x), single instr each.
__device__ __forceinline__ float fast_exp2(float x) { return __builtin_amdgcn_exp2f(x); }
__device__ __forceinline__ float fast_log2(float x) { return __builtin_amdgcn_logf(x); }

// ln sigmoid(xi - xj) = ln2 * (yi - log2(2^yi + 2^yj)),  y = x*log2(e), a = 2^y.
// Per (b,lvl): S = ln2 * (Ysum_lvl * below_lvl - LGsum_lvl); mean = S/(pos*below).
//
// ws layout (all deterministically overwritten every launch -> no memset):
//   float partials[3][NBLOCKS]; float yw[B_][3]; int cnt[B_][4]

__device__ __forceinline__ float combine_batch(const float* yw, const int* cnt,
                                               int b, float v0, float v1, float v2)
{
    const float LN2 = 0.693147180559945f;
    const int n0 = cnt[b*4+0], n1 = cnt[b*4+1], n2 = cnt[b*4+2], n3 = cnt[b*4+3];
    float msum = 0.0f, vsum = 0.0f;
    {
        const float c = (float)n1 * (float)n0;
        if (c > 0.0f) { msum += LN2 * (yw[b*3+0] * (float)n0 - v0) / c; vsum += 1.0f; }
    }
    {
        const int bl = n0 + n1;
        const float c = (float)n2 * (float)bl;
        if (c > 0.0f) { msum += LN2 * (yw[b*3+1] * (float)bl - v1) / c; vsum += 1.0f; }
    }
    {
        const int bl = n0 + n1 + n2;
        const float c = (float)n3 * (float)bl;
        if (c > 0.0f) { msum += LN2 * (yw[b*3+2] * (float)bl - v2) / c; vsum += 1.0f; }
    }
    return msum / fmaxf(vsum, 1.0f);
}

__global__ __launch_bounds__(256, 2) void bpr_fused_kernel(
    const float* __restrict__ logits,
    const int*   __restrict__ labels,
    float*       __restrict__ partials,
    float*       __restrict__ yw,
    int*         __restrict__ cnt,
    float*       __restrict__ out)
{
    __shared__ float    s_a[N_];       // label-sorted a = 2^y
    __shared__ unsigned wtot01[4], wtot23[4];
    __shared__ float    wred[4][3];    // per-wave level sums
    __shared__ float    yred[4][3];    // per-wave y sums
    __shared__ float    pg_s[B_];

    const int b     = blockIdx.x / NBLK;
    const int itile = blockIdx.x % NBLK;
    const int tid   = threadIdx.x;
    const int lane  = tid & 63;
    const int w     = tid >> 6;
    const float LOG2E = 1.442695040888963f;

    // ---- load 8 elements/thread (vectorized, coalesced) ----
    const float4* x4 = (const float4*)(logits + (size_t)b * N_);
    const int4*   l4 = (const int4*)(labels + (size_t)b * N_);
    const float4 xa = x4[tid], xb = x4[tid + 256];
    const int4   la = l4[tid], lb = l4[tid + 256];
    float y[8]; int lr[8];
    y[0]=xa.x*LOG2E; y[1]=xa.y*LOG2E; y[2]=xa.z*LOG2E; y[3]=xa.w*LOG2E;
    y[4]=xb.x*LOG2E; y[5]=xb.y*LOG2E; y[6]=xb.z*LOG2E; y[7]=xb.w*LOG2E;
    lr[0]=la.x; lr[1]=la.y; lr[2]=la.z; lr[3]=la.w;
    lr[4]=lb.x; lr[5]=lb.y; lr[6]=lb.z; lr[7]=lb.w;

    // ---- per-thread 4-bin counts + masked y-sums ----
    int c0=0,c1=0,c2=0,c3=0;
    float s1=0.0f, s2=0.0f, s3=0.0f;
    #pragma unroll
    for (int r = 0; r < 8; ++r) {
        c0 += (lr[r]==0); c1 += (lr[r]==1); c2 += (lr[r]==2); c3 += (lr[r]==3);
        s1 += (lr[r]==1) ? y[r] : 0.0f;
        s2 += (lr[r]==2) ? y[r] : 0.0f;
        s3 += (lr[r]==3) ? y[r] : 0.0f;
    }

    // ---- wave-level inclusive scan of packed counts (no barriers) ----
    const unsigned v01 = (unsigned)c0 | ((unsigned)c1 << 16);
    const unsigned v23 = (unsigned)c2 | ((unsigned)c3 << 16);
    unsigned i01 = v01, i23 = v23;
    #pragma unroll
    for (int off = 1; off < 64; off <<= 1) {
        const unsigned t01 = __shfl_up(i01, off);
        const unsigned t23 = __shfl_up(i23, off);
        if (lane >= off) { i01 += t01; i23 += t23; }
    }
    if (lane == 63) { wtot01[w] = i01; wtot23[w] = i23; }

    // y-sum wave reduce (cheap; only itile==0 block's result is used)
    float r1=s1, r2=s2, r3=s3;
    #pragma unroll
    for (int off = 32; off > 0; off >>= 1) {
        r1 += __shfl_xor(r1, off); r2 += __shfl_xor(r2, off); r3 += __shfl_xor(r3, off);
    }
    if (lane == 0) { yred[w][0]=r1; yred[w][1]=r2; yred[w][2]=r3; }
    __syncthreads();                               // barrier 1: wtot/yred ready

    unsigned p01 = 0, p23 = 0, g01 = 0, g23 = 0;
    #pragma unroll
    for (int k = 0; k < 4; ++k) {
        if (k < w) { p01 += wtot01[k]; p23 += wtot23[k]; }
        g01 += wtot01[k]; g23 += wtot23[k];
    }
    const int tot0 = (int)(g01 & 0xFFFFu), tot1 = (int)(g01 >> 16);
    const int tot2 = (int)(g23 & 0xFFFFu), tot3 = (int)(g23 >> 16);
    const int base1 = tot0, base2 = tot0 + tot1, base3 = tot0 + tot1 + tot2;

    const unsigned e01 = p01 + i01 - v01, e23 = p23 + i23 - v23;
    int o0 = (int)(e01 & 0xFFFFu);
    int o1 = base1 + (int)(e01 >> 16);
    int o2 = base2 + (int)(e23 & 0xFFFFu);
    int o3 = base3 + (int)(e23 >> 16);

    // ---- scatter a = 2^y into label-sorted LDS ----
    #pragma unroll
    for (int r = 0; r < 8; ++r) {
        const int l = lr[r];
        const int slot = (l==0) ? o0 : (l==1) ? o1 : (l==2) ? o2 : o3;
        o0 += (l==0); o1 += (l==1); o2 += (l==2); o3 += (l==3);
        s_a[slot] = fast_exp2(y[r]);
    }
    __syncthreads();                               // barrier 2: s_a ready

    if (itile == 0 && tid == 0) {
        cnt[b*4+0]=tot0; cnt[b*4+1]=tot1; cnt[b*4+2]=tot2; cnt[b*4+3]=tot3;
        yw[b*3+0] = yred[0][0]+yred[1][0]+yred[2][0]+yred[3][0];
        yw[b*3+1] = yred[0][1]+yred[1][1]+yred[2][1]+yred[3][1];
        yw[b*3+2] = yred[0][2]+yred[1][2]+yred[2][2]+yred[3][2];
    }

    // ---- pair loop: 2 rows/thread, b128 j-reads, 8-term log amortization ----
    const int rg = tid >> 3, jc = tid & 7;
    const int i0 = itile * ITILE + rg * 2, i1 = i0 + 1;
    const float ai0 = s_a[i0], ai1 = s_a[i1];
    const int li0 = (i0>=base1)+(i0>=base2)+(i0>=base3);
    const int li1 = (i1>=base1)+(i1>=base2)+(i1>=base3);
    const int bl0 = (li0==0)?0:(li0==1)?base1:(li0==2)?base2:base3;
    const int bl1 = (li1==0)?0:(li1==1)?base1:(li1==2)?base2:base3;
    const int blmin = min(bl0, bl1), blmax = max(bl0, bl1);

    const int j0 = jc * 4;
    const int ng  = (blmax > j0) ? ((blmax - j0 + 31) >> 5) : 0;
    const int ngf = (blmin >= j0 + 4) ? (((blmin - j0 - 4) >> 5) + 1) : 0;

    float acc0 = 0.0f, acc1 = 0.0f;
    float pr0 = 1.0f, pr1 = 1.0f;
    int j = j0, g = 0;
    for (; g < ngf; ++g) {                         // fully-valid groups: no masks
        const float4 aj = *(const float4*)&s_a[j];
        pr0 *= ((ai0+aj.x)*(ai0+aj.y)) * ((ai0+aj.z)*(ai0+aj.w));
        pr1 *= ((ai1+aj.x)*(ai1+aj.y)) * ((ai1+aj.z)*(ai1+aj.w));
        if (g & 1) { acc0 += fast_log2(pr0); pr0 = 1.0f;
                     acc1 += fast_log2(pr1); pr1 = 1.0f; }
        j += 32;
    }
    for (; g < ng; ++g) {                          // <=2 boundary groups: masked
        const float4 aj = *(const float4*)&s_a[j];
        pr0 *= (j+0<bl0 ? ai0+aj.x : 1.0f) * (j+1<bl0 ? ai0+aj.y : 1.0f)
             * (j+2<bl0 ? ai0+aj.z : 1.0f) * (j+3<bl0 ? ai0+aj.w : 1.0f);
        pr1 *= (j+0<bl1 ? ai1+aj.x : 1.0f) * (j+1<bl1 ? ai1+aj.y : 1.0f)
             * (j+2<bl1 ? ai1+aj.z : 1.0f) * (j+3<bl1 ? ai1+aj.w : 1.0f);
        if (g & 1) { acc0 += fast_log2(pr0); pr0 = 1.0f;
                     acc1 += fast_log2(pr1); pr1 = 1.0f; }
        j += 32;
    }
    acc0 += fast_log2(pr0);                        // flush (log2(1)==0)
    acc1 += fast_log2(pr1);

    // ---- register level-accumulate (no atomics) + block reduce ----
    float aL0 = ((li0==1)?acc0:0.0f) + ((li1==1)?acc1:0.0f);
    float aL1 = ((li0==2)?acc0:0.0f) + ((li1==2)?acc1:0.0f);
    float aL2 = ((li0==3)?acc0:0.0f) + ((li1==3)?acc1:0.0f);
    #pragma unroll
    for (int off = 32; off > 0; off >>= 1) {
        aL0 += __shfl_xor(aL0, off); aL1 += __shfl_xor(aL1, off); aL2 += __shfl_xor(aL2, off);
    }
    if (lane == 0) { wred[w][0]=aL0; wred[w][1]=aL1; wred[w][2]=aL2; }
    __syncthreads();                               // barrier 3
    if (tid < 3)
        partials[tid * NBLOCKS + blockIdx.x] =
            wred[0][tid] + wred[1][tid] + wred[2][tid] + wred[3][tid];

    // ---- grid-wide barrier, then block 0 finalizes (one kernel node) ----
    cg::this_grid().sync();

    if (blockIdx.x == 0) {
        // thread t reduces partials for blk=t (batch t>>5) and blk=t+256 (batch 8+(t>>5))
        float a0 = partials[0*NBLOCKS + tid];
        float a1 = partials[1*NBLOCKS + tid];
        float a2 = partials[2*NBLOCKS + tid];
        float b0 = partials[0*NBLOCKS + tid + 256];
        float b1 = partials[1*NBLOCKS + tid + 256];
        float b2 = partials[2*NBLOCKS + tid + 256];
        #pragma unroll
        for (int off = 16; off > 0; off >>= 1) {   // reduce within 32-lane groups
            a0 += __shfl_xor(a0, off); a1 += __shfl_xor(a1, off); a2 += __shfl_xor(a2, off);
            b0 += __shfl_xor(b0, off); b1 += __shfl_xor(b1, off); b2 += __shfl_xor(b2, off);
        }
        if ((tid & 31) == 0) {
            const int bb = tid >> 5;               // 0..7
            pg_s[bb]     = combine_batch(yw, cnt, bb,     a0, a1, a2);
            pg_s[bb + 8] = combine_batch(yw, cnt, bb + 8, b0, b1, b2);
        }
        __syncthreads();
        if (tid == 0) {
            float total = 0.0f;
            #pragma unroll
            for (int k = 0; k < B_; ++k) total += pg_s[k];
            out[0] = -total / (float)B_;
        }
    }
}

extern "C" void kernel_launch(void* const* d_in, const int* in_sizes, int n_in,
                              void* d_out, int out_size, void* d_ws, size_t ws_size,
                              hipStream_t stream)
{
    const float* logits   = (const float*)d_in[0];
    const int*   labels   = (const int*)d_in[1];
    float*       out      = (float*)d_out;
    float*       partials = (float*)d_ws;
    float*       ywp      = (float*)((char*)d_ws + 3 * NBLOCKS * sizeof(float));
    int*         cntp     = (int*)((char*)d_ws + (3 * NBLOCKS + 3 * B_) * sizeof(float));

    void* args[] = { (void*)&logits, (void*)&labels, (void*)&partials,
                     (void*)&ywp, (void*)&cntp, (void*)&out };
    (void)hipLaunchCooperativeKernel((const void*)bpr_fused_kernel,
                                     dim3(NBLOCKS), dim3(256), args, 0, stream);
}

// Round 9
// 14.995 us; speedup vs baseline: 4.6085x; 4.6085x over previous
//
#include <hip/hip_runtime.h>

#define B_ 16
#define N_ 2048
#define ITILE 64                   // rows per block (as 4 strided 16-row wave-chunks)
#define NBLK (N_ / ITILE)          // 32 blocks per batch
#define NBLOCKS (B_ * NBLK)        // 512 total

// HW transcendentals: v_exp_f32 (2^x) and v_log_f32 (log2 x), single instr each.
__device__ __forceinline__ float fast_exp2(float x) { return __builtin_amdgcn_exp2f(x); }
__device__ __forceinline__ float fast_log2(float x) { return __builtin_amdgcn_logf(x); }

// ln sigmoid(xi - xj) = ln2 * (yi - log2(2^yi + 2^yj)),  y = x*log2(e), a = 2^y.
// Per (b,lvl): S = ln2 * (Ysum_lvl * below_lvl - LGsum_lvl); mean = S/(pos*below).
//
// ws layout (all deterministically overwritten every launch -> no memset):
//   float partials[3][NBLOCKS]; float yw[B_][3]; int cnt[B_][4]

__global__ __launch_bounds__(256) void bpr_pair_kernel(
    const float* __restrict__ logits,
    const int*   __restrict__ labels,
    float*       __restrict__ partials,
    float*       __restrict__ yw,
    int*         __restrict__ cnt)
{
    __shared__ float    s_a[N_];       // label-sorted a = 2^y
    __shared__ unsigned wtot01[4], wtot23[4];
    __shared__ float    wred[4][3];    // per-wave level sums
    __shared__ float    yred[4][3];    // per-wave y sums

    const int b     = blockIdx.x / NBLK;
    const int itile = blockIdx.x % NBLK;
    const int tid   = threadIdx.x;
    const int lane  = tid & 63;
    const int w     = tid >> 6;
    const float LOG2E = 1.442695040888963f;

    // ---- load 8 elements/thread (vectorized, coalesced) ----
    const float4* x4 = (const float4*)(logits + (size_t)b * N_);
    const int4*   l4 = (const int4*)(labels + (size_t)b * N_);
    const float4 xa = x4[tid], xb = x4[tid + 256];
    const int4   la = l4[tid], lb = l4[tid + 256];
    float y[8]; int lr[8];
    y[0]=xa.x*LOG2E; y[1]=xa.y*LOG2E; y[2]=xa.z*LOG2E; y[3]=xa.w*LOG2E;
    y[4]=xb.x*LOG2E; y[5]=xb.y*LOG2E; y[6]=xb.z*LOG2E; y[7]=xb.w*LOG2E;
    lr[0]=la.x; lr[1]=la.y; lr[2]=la.z; lr[3]=la.w;
    lr[4]=lb.x; lr[5]=lb.y; lr[6]=lb.z; lr[7]=lb.w;

    // ---- per-thread 4-bin counts + masked y-sums ----
    int c0=0,c1=0,c2=0,c3=0;
    float s1=0.0f, s2=0.0f, s3=0.0f;
    #pragma unroll
    for (int r = 0; r < 8; ++r) {
        c0 += (lr[r]==0); c1 += (lr[r]==1); c2 += (lr[r]==2); c3 += (lr[r]==3);
        s1 += (lr[r]==1) ? y[r] : 0.0f;
        s2 += (lr[r]==2) ? y[r] : 0.0f;
        s3 += (lr[r]==3) ? y[r] : 0.0f;
    }

    // ---- wave-level inclusive scan of packed counts (no barriers) ----
    const unsigned v01 = (unsigned)c0 | ((unsigned)c1 << 16);
    const unsigned v23 = (unsigned)c2 | ((unsigned)c3 << 16);
    unsigned i01 = v01, i23 = v23;
    #pragma unroll
    for (int off = 1; off < 64; off <<= 1) {
        const unsigned t01 = __shfl_up(i01, off);
        const unsigned t23 = __shfl_up(i23, off);
        if (lane >= off) { i01 += t01; i23 += t23; }
    }
    if (lane == 63) { wtot01[w] = i01; wtot23[w] = i23; }

    // y-sum wave reduce (cheap; only itile==0 block's result is used)
    float r1=s1, r2=s2, r3=s3;
    #pragma unroll
    for (int off = 32; off > 0; off >>= 1) {
        r1 += __shfl_xor(r1, off); r2 += __shfl_xor(r2, off); r3 += __shfl_xor(r3, off);
    }
    if (lane == 0) { yred[w][0]=r1; yred[w][1]=r2; yred[w][2]=r3; }
    __syncthreads();                               // barrier 1: wtot/yred ready

    unsigned p01 = 0, p23 = 0, g01 = 0, g23 = 0;
    #pragma unroll
    for (int k = 0; k < 4; ++k) {
        if (k < w) { p01 += wtot01[k]; p23 += wtot23[k]; }
        g01 += wtot01[k]; g23 += wtot23[k];
    }
    const int tot0 = (int)(g01 & 0xFFFFu), tot1 = (int)(g01 >> 16);
    const int tot2 = (int)(g23 & 0xFFFFu), tot3 = (int)(g23 >> 16);
    const int base1 = tot0, base2 = tot0 + tot1, base3 = tot0 + tot1 + tot2;

    const unsigned e01 = p01 + i01 - v01, e23 = p23 + i23 - v23;
    int o0 = (int)(e01 & 0xFFFFu);
    int o1 = base1 + (int)(e01 >> 16);
    int o2 = base2 + (int)(e23 & 0xFFFFu);
    int o3 = base3 + (int)(e23 >> 16);

    // ---- scatter a = 2^y into label-sorted LDS ----
    #pragma unroll
    for (int r = 0; r < 8; ++r) {
        const int l = lr[r];
        const int slot = (l==0) ? o0 : (l==1) ? o1 : (l==2) ? o2 : o3;
        o0 += (l==0); o1 += (l==1); o2 += (l==2); o3 += (l==3);
        s_a[slot] = fast_exp2(y[r]);
    }
    __syncthreads();                               // barrier 2: s_a ready

    if (itile == 0 && tid == 0) {
        cnt[b*4+0]=tot0; cnt[b*4+1]=tot1; cnt[b*4+2]=tot2; cnt[b*4+3]=tot3;
        yw[b*3+0] = yred[0][0]+yred[1][0]+yred[2][0]+yred[3][0];
        yw[b*3+1] = yred[0][1]+yred[1][1]+yred[2][1]+yred[3][1];
        yw[b*3+2] = yred[0][2]+yred[1][2]+yred[2][2]+yred[3][2];
    }

    // ---- pair loop: wave-chunk strided rows for load balance ----
    // Per batch: 128 waves, 128 contiguous 16-row chunks of the sorted array.
    // Wave (itile,w) takes chunk w*NBLK+itile: contiguous rows within the wave
    // (uniform trip counts), quartile-strided across blocks (balanced blocks).
    const int chunk = w * NBLK + itile;            // 0..127
    const int rg = lane >> 3, jc = lane & 7;       // row-group in chunk, j-lane
    const int i0 = chunk * 16 + rg * 2, i1 = i0 + 1;
    const float ai0 = s_a[i0], ai1 = s_a[i1];
    const int li0 = (i0>=base1)+(i0>=base2)+(i0>=base3);
    const int li1 = (i1>=base1)+(i1>=base2)+(i1>=base3);
    const int bl0 = (li0==0)?0:(li0==1)?base1:(li0==2)?base2:base3;
    const int bl1 = (li1==0)?0:(li1==1)?base1:(li1==2)?base2:base3;
    const int blmin = min(bl0, bl1), blmax = max(bl0, bl1);

    const int j0 = jc * 4;
    const int ng  = (blmax > j0) ? ((blmax - j0 + 31) >> 5) : 0;
    const int ngf = (blmin >= j0 + 4) ? (((blmin - j0 - 4) >> 5) + 1) : 0;

    float acc0 = 0.0f, acc1 = 0.0f;
    float pr0 = 1.0f, pr1 = 1.0f;
    int j = j0, g = 0;
    for (; g < ngf; ++g) {                         // fully-valid groups: no masks
        const float4 aj = *(const float4*)&s_a[j];
        pr0 *= ((ai0+aj.x)*(ai0+aj.y)) * ((ai0+aj.z)*(ai0+aj.w));
        pr1 *= ((ai1+aj.x)*(ai1+aj.y)) * ((ai1+aj.z)*(ai1+aj.w));
        if (g & 1) { acc0 += fast_log2(pr0); pr0 = 1.0f;
                     acc1 += fast_log2(pr1); pr1 = 1.0f; }
        j += 32;
    }
    for (; g < ng; ++g) {                          // <=2 boundary groups: masked
        const float4 aj = *(const float4*)&s_a[j];
        pr0 *= (j+0<bl0 ? ai0+aj.x : 1.0f) * (j+1<bl0 ? ai0+aj.y : 1.0f)
             * (j+2<bl0 ? ai0+aj.z : 1.0f) * (j+3<bl0 ? ai0+aj.w : 1.0f);
        pr1 *= (j+0<bl1 ? ai1+aj.x : 1.0f) * (j+1<bl1 ? ai1+aj.y : 1.0f)
             * (j+2<bl1 ? ai1+aj.z : 1.0f) * (j+3<bl1 ? ai1+aj.w : 1.0f);
        if (g & 1) { acc0 += fast_log2(pr0); pr0 = 1.0f;
                     acc1 += fast_log2(pr1); pr1 = 1.0f; }
        j += 32;
    }
    acc0 += fast_log2(pr0);                        // flush (log2(1)==0)
    acc1 += fast_log2(pr1);

    // ---- register level-accumulate (no atomics) + block reduce ----
    float aL0 = ((li0==1)?acc0:0.0f) + ((li1==1)?acc1:0.0f);
    float aL1 = ((li0==2)?acc0:0.0f) + ((li1==2)?acc1:0.0f);
    float aL2 = ((li0==3)?acc0:0.0f) + ((li1==3)?acc1:0.0f);
    #pragma unroll
    for (int off = 32; off > 0; off >>= 1) {
        aL0 += __shfl_xor(aL0, off); aL1 += __shfl_xor(aL1, off); aL2 += __shfl_xor(aL2, off);
    }
    if (lane == 0) { wred[w][0]=aL0; wred[w][1]=aL1; wred[w][2]=aL2; }
    __syncthreads();                               // barrier 3
    if (tid < 3)
        partials[tid * NBLOCKS + blockIdx.x] =
            wred[0][tid] + wred[1][tid] + wred[2][tid] + wred[3][tid];
}

// One block, 512 threads: 32 lanes per batch reduce its 32 block-partials.
__global__ __launch_bounds__(512) void bpr_finalize(
    const float* __restrict__ partials,
    const float* __restrict__ yw,
    const int*   __restrict__ cnt,
    float*       __restrict__ out)
{
    __shared__ float pg_s[B_];
    const int tid = threadIdx.x;

    float v0 = partials[0 * NBLOCKS + tid];
    float v1 = partials[1 * NBLOCKS + tid];
    float v2 = partials[2 * NBLOCKS + tid];
    #pragma unroll
    for (int off = 16; off > 0; off >>= 1) {       // reduce within 32-lane groups
        v0 += __shfl_xor(v0, off); v1 += __shfl_xor(v1, off); v2 += __shfl_xor(v2, off);
    }

    const int b = tid >> 5;
    if ((tid & 31) == 0) {
        const float LN2 = 0.693147180559945f;
        const int n0 = cnt[b*4+0], n1 = cnt[b*4+1], n2 = cnt[b*4+2], n3 = cnt[b*4+3];
        float msum = 0.0f, vsum = 0.0f;
        {
            const float c = (float)n1 * (float)n0;
            if (c > 0.0f) { msum += LN2 * (yw[b*3+0] * (float)n0 - v0) / c; vsum += 1.0f; }
        }
        {
            const int bl = n0 + n1;
            const float c = (float)n2 * (float)bl;
            if (c > 0.0f) { msum += LN2 * (yw[b*3+1] * (float)bl - v1) / c; vsum += 1.0f; }
        }
        {
            const int bl = n0 + n1 + n2;
            const float c = (float)n3 * (float)bl;
            if (c > 0.0f) { msum += LN2 * (yw[b*3+2] * (float)bl - v2) / c; vsum += 1.0f; }
        }
        pg_s[b] = msum / fmaxf(vsum, 1.0f);
    }
    __syncthreads();
    if (tid == 0) {
        float total = 0.0f;
        #pragma unroll
        for (int k = 0; k < B_; ++k) total += pg_s[k];
        out[0] = -total / (float)B_;
    }
}

extern "C" void kernel_launch(void* const* d_in, const int* in_sizes, int n_in,
                              void* d_out, int out_size, void* d_ws, size_t ws_size,
                              hipStream_t stream)
{
    const float* logits   = (const float*)d_in[0];
    const int*   labels   = (const int*)d_in[1];
    float*       out      = (float*)d_out;
    float*       partials = (float*)d_ws;
    float*       ywp      = (float*)((char*)d_ws + 3 * NBLOCKS * sizeof(float));
    int*         cntp     = (int*)((char*)d_ws + (3 * NBLOCKS + 3 * B_) * sizeof(float));

    // No memset: every ws slot used is overwritten every launch.
    bpr_pair_kernel<<<dim3(NBLOCKS), 256, 0, stream>>>(logits, labels, partials, ywp, cntp);
    bpr_finalize<<<1, 512, 0, stream>>>(partials, ywp, cntp, out);
}